// Round 9
// baseline (400.426 us; speedup 1.0000x reference)
//
#include <hip/hip_runtime.h>
#include <math.h>

// Problem constants (fixed by setup_inputs): B=8, C=4, H=W=64, K=8192
#define N_POINTS 32768   // B*H*W
#define KCODES   8192
#define HW       4096
#define CHW      16384
#define NSEG     128
#define SEGLEN   (KCODES / NSEG)   // 64 codes per segment (1 per lane)
#define PPT      8                 // points per thread (R0-proven)
#define PTILE    (64 * PPT)        // 512 points per 1-wave block
#define GRIDX    (N_POINTS / PTILE) // 64 -> grid 64x128 = 8192 blocks

// ws layout: packed u64[32768] @ 0  ((sortable(best_d2)<<32)|best_k)
#define WS_PACKED 0

// Bit-exact conv z = W x + b, numpy sequential c-order, no FMA contraction.
__device__ __forceinline__ void compute_z(
    const float* __restrict__ ze, const float* __restrict__ w,
    const float* __restrict__ bias, int n, float zo[4], float& zz) {
  int b = n >> 12, hw = n & 4095;
  const float* p = ze + b * CHW + hw;
  float x0 = p[0], x1 = p[HW], x2 = p[2 * HW], x3 = p[3 * HW];
#pragma unroll
  for (int o = 0; o < 4; ++o) {
    float acc = __fmul_rn(x0, w[o * 4 + 0]);
    acc = __fadd_rn(acc, __fmul_rn(x1, w[o * 4 + 1]));
    acc = __fadd_rn(acc, __fmul_rn(x2, w[o * 4 + 2]));
    acc = __fadd_rn(acc, __fmul_rn(x3, w[o * 4 + 3]));
    zo[o] = __fadd_rn(acc, bias[o]);
  }
  float s = __fmul_rn(zo[0], zo[0]);
  s = __fadd_rn(s, __fmul_rn(zo[1], zo[1]));
  s = __fadd_rn(s, __fmul_rn(zo[2], zo[2]));
  s = __fadd_rn(s, __fmul_rn(zo[3], zo[3]));
  zz = s;
}

// ---------------- Kernel S: 1-wave scan at 8 waves/SIMD --------------------
// Inner loop VERBATIM from the proven baseline (R0). R1-R8 lessons: (a) any
// reshaping of the inner arithmetic inflates emitted VALU 1.6-2.2x; (b) the
// wall-busy gap (~25% idle issue) is NOT barriers/drain/atomics (R8 removed
// all three: neutral). Remaining suspect: latency-hiding capacity — 4
// waves/SIMD stall in-phase on lgkmcnt/global waits. This round doubles
// occupancy to 8 waves/SIMD (HW cap 32 waves/CU) via NSEG 64->128 at
// VGPR=60 <= 64 (the 8-wave ceiling), inner loop untouched: per-code VALU
// +1.8%, atomic traffic 33MB (~5us BW, proven non-binding in R7).
// Pre-commitment: scan >= 58us here => structure is at its floor, ROOFLINE.
__global__ __launch_bounds__(64, 8) void vq_scan(
    const float* __restrict__ ze, const float* __restrict__ w,
    const float* __restrict__ bias, const float* __restrict__ cb,
    unsigned long long* __restrict__ packed) {
  __shared__ float4 s_c[SEGLEN];            // 2*codebook segment (1024 B)
  __shared__ float  s_n[SEGLEN];            // |c|^2 segment (256 B)
  int lane = threadIdx.x;                   // 0..63, one wave per block
  int k0 = blockIdx.y * SEGLEN;
  // transform+stage 1 code per lane (doubling by 2 is exact bitwise)
  {
    float4 c = ((const float4*)cb)[k0 + lane];
    s_c[lane] = make_float4(2.f * c.x, 2.f * c.y, 2.f * c.z, 2.f * c.w);
    float s = __fmul_rn(c.x, c.x);
    s = __fadd_rn(s, __fmul_rn(c.y, c.y));
    s = __fadd_rn(s, __fmul_rn(c.z, c.z));
    s = __fadd_rn(s, __fmul_rn(c.w, c.w));
    s_n[lane] = s;
  }
  // conv for this wave's 8 points while the staging writes land
  int n0 = blockIdx.x * PTILE + lane;       // points n0 + 64*p, coalesced
  float z[PPT][4], zz[PPT], best[PPT];
  int bidx[PPT];
#pragma unroll
  for (int p = 0; p < PPT; ++p) {
    compute_z(ze, w, bias, n0 + 64 * p, z[p], zz[p]);
    best[p] = INFINITY;
    bidx[p] = 0;
  }
  __builtin_amdgcn_wave_barrier();          // same-wave ds order; no s_barrier
  // ---- double-buffered chunk loop (4 codes/chunk, ascending k) ----
  float4 cA[4], nA;
  cA[0] = s_c[0]; cA[1] = s_c[1]; cA[2] = s_c[2]; cA[3] = s_c[3];
  nA = *(const float4*)&s_n[0];
  for (int kc = 0; kc < SEGLEN; kc += 4) {
    int kn = (kc + 4) & (SEGLEN - 1);       // wraps harmlessly on last iter
    float4 cB[4], nB;
    cB[0] = s_c[kn + 0]; cB[1] = s_c[kn + 1];
    cB[2] = s_c[kn + 2]; cB[3] = s_c[kn + 3];
    nB = *(const float4*)&s_n[kn];
    float cnr[4] = {nA.x, nA.y, nA.z, nA.w};
#pragma unroll
    for (int r = 0; r < 4; ++r) {
      int kk = k0 + kc + r;                 // ascending k: strict < = first-min
#pragma unroll
      for (int p = 0; p < PPT; ++p) {
        // 2*dot with numpy's sequential rounding order (doubling is exact)
        float d = __fmul_rn(z[p][0], cA[r].x);
        d = __fadd_rn(d, __fmul_rn(z[p][1], cA[r].y));
        d = __fadd_rn(d, __fmul_rn(z[p][2], cA[r].z));
        d = __fadd_rn(d, __fmul_rn(z[p][3], cA[r].w));
        // ref: (|z|^2 - 2*dot) + |c|^2, left-to-right
        float s = __fadd_rn(__fsub_rn(zz[p], d), cnr[r]);
        if (s < best[p]) { best[p] = s; bidx[p] = kk; }
      }
    }
    cA[0] = cB[0]; cA[1] = cB[1]; cA[2] = cB[2]; cA[3] = cB[3];
    nA = nB;
  }
#pragma unroll
  for (int p = 0; p < PPT; ++p) {
    // pack (sortable float, k): u64 min == (min value, then min k)
    unsigned int u = __float_as_uint(best[p]);
    unsigned int so = (u & 0x80000000u) ? ~u : (u | 0x80000000u);
    unsigned long long key =
        ((unsigned long long)so << 32) | (unsigned int)bidx[p];
    atomicMin(&packed[n0 + 64 * p], key);
  }
}

// ---------------- Kernel F: decode, gather, latent write, loss -------------
// Unchanged from the 115.96us baseline (bit-exact, absmax=0 proven).
__global__ __launch_bounds__(256) void vq_finish(
    const float* __restrict__ ze, const float* __restrict__ w,
    const float* __restrict__ bias, const float* __restrict__ cb,
    const unsigned long long* __restrict__ packed, float* __restrict__ out) {
  int n = blockIdx.x * 256 + threadIdx.x;
  int bidx = (unsigned int)(packed[n] & 0xFFFFFFFFull);
  float4 c = ((const float4*)cb)[bidx];     // bit-exact gather (16B aligned)
  int b = n >> 12, hw = n & 4095;
  float* o = out + b * CHW + hw;
  o[0] = c.x; o[HW] = c.y; o[2 * HW] = c.z; o[3 * HW] = c.w;
  float z[4], zz;
  compute_z(ze, w, bias, n, z, zz);
  float d0 = c.x - z[0], d1 = c.y - z[1], d2 = c.z - z[2], d3 = c.w - z[3];
  float e = d0 * d0 + d1 * d1 + d2 * d2 + d3 * d3;
#pragma unroll
  for (int off = 32; off > 0; off >>= 1) e += __shfl_down(e, off, 64);
  __shared__ float sred[4];
  if ((threadIdx.x & 63) == 0) sred[threadIdx.x >> 6] = e;
  __syncthreads();
  if (threadIdx.x == 0) {
    float t = (sred[0] + sred[1]) + (sred[2] + sred[3]);
    // q_loss = (1 + BETA) * mean over 131072 elements
    atomicAdd(out + (N_POINTS * 4), t * (1.25f / 131072.f));
  }
}

extern "C" void kernel_launch(void* const* d_in, const int* in_sizes, int n_in,
                              void* d_out, int out_size, void* d_ws, size_t ws_size,
                              hipStream_t stream) {
  const float* ze   = (const float*)d_in[0];  // z_e_in [8,4,64,64]
  const float* w    = (const float*)d_in[1];  // pq_w [4,4]
  const float* bias = (const float*)d_in[2];  // pq_b [4]
  const float* cb   = (const float*)d_in[3];  // codebook [8192,4]

  unsigned long long* packed =
      (unsigned long long*)((char*)d_ws + WS_PACKED);
  float* out = (float*)d_out;

  // poison packed (0xFF == u64 max == sortable max) + zero loss (R4-proven)
  hipMemsetAsync(packed, 0xFF, N_POINTS * sizeof(unsigned long long), stream);
  hipMemsetAsync((char*)d_out + (size_t)N_POINTS * 4 * sizeof(float), 0,
                 sizeof(float), stream);
  vq_scan<<<dim3(GRIDX, NSEG), 64, 0, stream>>>(ze, w, bias, cb, packed);
  vq_finish<<<128, 256, 0, stream>>>(ze, w, bias, cb, packed, out);
}